// Round 9
// baseline (1209.697 us; speedup 1.0000x reference)
//
#include <hip/hip_runtime.h>
#include <cstdint>
#include <cstddef>

// FeedForward: GroupNorm(8) -> conv1x1 C->2C -> GELU(exact) -> conv1x1 2C->C -> +x
// B=16, C=512, L=4096. ALL I/O FP32. Internal: bf16 MFMA, fp32 accum.
//
// R13 changes vs R12 (514us, regression) / R11 (481.8us baseline):
//  - DISCOVERY: gemm dispatch-ID periods (R12: 13 = 1+NC*3; R6: 14 = 2+NC*3)
//    prove NC=4 (ws ~50-98MiB), i.e. each gemm dispatch is a QUARTER chunk
//    (gemm1 1024 blocks, gemm2 512). Top-5 durations (133-170us) are
//    cold-start outliers (4x those would exceed wall time); warm chunks run
//    ~55us (~310 TF). All prior counter analysis was on outliers.
//  - BKK=32 reverted (8.4M bank conflicts: 64B rows -> bank=f(slot) only).
//  - GEMM core: register-staged double-buffer (T14). Loads for tile t+1 go
//    global->VGPR (issued before compute t), ds_write->single 32KB LDS buffer
//    after the barrier. LDS 64->32KB => 3 blocks/CU (launch_bounds(256,3)).
//    Compiler auto-inserts vmcnt at the ds_write consumers -- no inline asm,
//    no global_load_lds/ds_read waitcnt-pass pathology, no endpgm drain
//    hazard. Read path + zero-conflict XOR swizzle unchanged from R6/R11
//    (XOR in the (now register) global load address, LDS linear).
//  - Kept: fused gn_stats+conv_w (R12), R11 gn_norm_tr, A&S erf GELU,
//    swapped mfma(bb,af) vectorized epilogues, XCD swizzles.

typedef unsigned short u16;
typedef unsigned int u32;
typedef __attribute__((ext_vector_type(8))) __bf16 bf16x8;
typedef __attribute__((ext_vector_type(4))) float floatx4;

#define BM 128
#define BN 128
#define BKK 64

__device__ __forceinline__ u16 f2bf(float f) {
    union { float f; u32 u; } v; v.f = f;
    u32 u = v.u;
    return (u16)((u + 0x7fffu + ((u >> 16) & 1u)) >> 16);  // RNE
}

// GELU(v) = 0.5 v (1 + erf(v/sqrt(2))); erf via A&S 7.1.26, |err| <= 1.5e-7.
__device__ __forceinline__ float gelu_exact(float v) {
    const float x = fabsf(v) * 0.70710678118654752f;
    const float t = __builtin_amdgcn_rcpf(fmaf(0.3275911f, x, 1.0f));
    float p = fmaf(1.061405429f, t, -1.453152027f);
    p = fmaf(p, t, 1.421413741f);
    p = fmaf(p, t, -0.284496736f);
    p = fmaf(p, t, 0.254829592f);
    p = p * t;
    const float e = __expf(-x * x);            // v_exp_f32
    const float er = fmaf(-p, e, 1.0f);        // erf(|x|)
    const float s = copysignf(er, v);          // sign restore
    return 0.5f * v * (1.0f + s);
}

// ---------------- kernel 1: partial group stats + weight cast (fused) ----------------
__global__ __launch_bounds__(256) void gn_stats_w(const float* __restrict__ x,
                                                  float* __restrict__ pstats,
                                                  const float* __restrict__ w1,
                                                  const float* __restrict__ w2,
                                                  u16* __restrict__ wb) {
    const int bx = blockIdx.x;
    if (bx >= 1024) {  // weight cast: 1024 blocks x 1024 floats
        const int idx = ((bx - 1024) * 256 + threadIdx.x) * 4;  // < 1048576
        const float4 v = (idx < 524288) ? *(const float4*)(w1 + idx)
                                        : *(const float4*)(w2 + (idx - 524288));
        ushort4 o;
        o.x = f2bf(v.x); o.y = f2bf(v.y); o.z = f2bf(v.z); o.w = f2bf(v.w);
        *(ushort4*)(wb + idx) = o;
        return;
    }
    // stats: bx = bg*8 + slice
    const float4* p = (const float4*)(x + (size_t)(bx >> 3) * 262144 + (size_t)(bx & 7) * 32768);
    float s = 0.f, ss = 0.f;
    for (int i = threadIdx.x; i < 8192; i += 256) {
        float4 v = p[i];
        s += v.x + v.y + v.z + v.w;
        ss += v.x * v.x + v.y * v.y + v.z * v.z + v.w * v.w;
    }
#pragma unroll
    for (int off = 32; off > 0; off >>= 1) {
        s  += __shfl_down(s, off, 64);
        ss += __shfl_down(ss, off, 64);
    }
    __shared__ float rs[8];
    const int wv = threadIdx.x >> 6;
    if ((threadIdx.x & 63) == 0) { rs[wv * 2] = s; rs[wv * 2 + 1] = ss; }
    __syncthreads();
    if (threadIdx.x == 0) {
        pstats[bx * 2]     = rs[0] + rs[2] + rs[4] + rs[6];
        pstats[bx * 2 + 1] = rs[1] + rs[3] + rs[5] + rs[7];
    }
}

// ---------------- kernel 3: normalize + transpose (fp32 -> bf16) ----------------
// 4 l-subtiles (64l x 64c each) per block; 4 T-buffers so ALL loads are in
// flight before the single barrier.
__global__ __launch_bounds__(256) void gn_norm_tr(const float* __restrict__ x,
                                                  const float* __restrict__ gamma,
                                                  const float* __restrict__ beta,
                                                  const float* __restrict__ pstats,
                                                  u16* __restrict__ xnT, int b0) {
    __shared__ u16 T[4][64][72];  // [q][l][c], c-groups XOR-swizzled by (l>>3)&7
    const int bx = blockIdx.x;
    const int l4 = bx & 15;          // 16 l-supertiles of 256
    const int ct = (bx >> 4) & 7;    // 8 c-tiles (== groups)
    const int bl = bx >> 7;          // batch within chunk
    const int b = b0 + bl;
    const int c0 = ct * 64, l0 = l4 * 256;
    const int g = ct;                // tile spans exactly one group
    float S = 0.f, SS = 0.f;
#pragma unroll
    for (int s2 = 0; s2 < 8; ++s2) {
        S  += pstats[((b * 8 + g) * 8 + s2) * 2];
        SS += pstats[((b * 8 + g) * 8 + s2) * 2 + 1];
    }
    const float inv = 1.f / 262144.f;
    const float mean = S * inv;
    const float var = SS * inv - mean * mean;  // population var (jnp.var)
    const float rstd = rsqrtf(var + 1e-5f);

    const int t = threadIdx.x;
    const int cl = t >> 3;          // 0..31  (c within tile, low 32)
    const int lo = (t & 7) * 8;     // 8 l's per thread
    const int sw = t & 7;           // == (l>>3)&7 for this thread's l's
#pragma unroll
    for (int h = 0; h < 2; ++h) {
        const int c = c0 + cl + h * 32;
        const float sc = rstd * gamma[c];
        const float sh = beta[c] - mean * sc;
        const int ccol = cl + h * 32;
        const int col = (((ccol >> 3) ^ sw) << 3) + (ccol & 7);
        const float* srcr = x + ((size_t)(b * 512 + c) * 4096 + l0 + lo);
#pragma unroll
        for (int q = 0; q < 4; ++q) {
            const float* src = srcr + q * 64;
            float4 a = *(const float4*)src;
            float4 bq = *(const float4*)(src + 4);
            float vv[8] = {a.x, a.y, a.z, a.w, bq.x, bq.y, bq.z, bq.w};
#pragma unroll
            for (int k = 0; k < 8; ++k)
                T[q][lo + k][col] = f2bf(fmaf(vv[k], sc, sh));
        }
    }
    __syncthreads();
    const int ll = t >> 3;
    const int co = (t & 7) * 8, cog = t & 7;
#pragma unroll
    for (int h = 0; h < 2; ++h) {
        const int l = ll + h * 32;
        const int colb = (cog ^ ((l >> 3) & 7)) << 3;
#pragma unroll
        for (int q = 0; q < 4; ++q) {
            const uint4* srcv = (const uint4*)&T[q][l][colb];
            *(uint4*)(xnT + ((size_t)(bl * 4096 + l0 + q * 64 + l) * 512 + c0 + co)) = *srcv;
        }
    }
}

// ---------------- GEMM core (gemm_bt): C[m][n] = sum_k A[m][k]*B[n][k] ----------------
// Register-staged double-buffer (T14): per K-step, the NEXT tile's 8 uint4
// loads are issued right after the barrier (before fragment reads + MFMA), so
// they have the whole compute phase + barrier to land. ds_write (consumer)
// gets a compiler-inserted vmcnt wait. Single 32KB LDS buffer -> 3 blocks/CU.
// Addressing identical to R6: XOR k-swizzle in the GLOBAL address (LDS
// linear); LDS row r slot s holds k-group s^(r&7); read slot = ((kk>>3)+quad)
// ^ (fr&7) -- measured zero bank conflicts.
// MFMA operand order SWAPPED (bb first): C/D maps col=lane&15 -> m (af rows),
// row=quad*4+reg -> n (bb rows) -> lane's 4 acc regs are consecutive n.
__device__ __forceinline__ void gemm_core(const u16* __restrict__ Ag,  // [*][K] bf16
                                          const u16* __restrict__ Bg,  // [*][K] bf16
                                          int K, floatx4 acc[4][4],
                                          u16* lA, u16* lB,
                                          int wm, int wn, int fr, int quad) {
    const int t = threadIdx.x;
    uint4 ra[4], rb[4];

    // per-thread staging source bases (idx = s*256 + t)
    const u16* sa[4]; const u16* sb[4];
#pragma unroll
    for (int s = 0; s < 4; ++s) {
        const int idx = s * 256 + t;
        const int row = idx >> 3;
        const int kg = (idx & 7) ^ (row & 7);
        sa[s] = Ag + (size_t)row * K + kg * 8;
        sb[s] = Bg + (size_t)row * K + kg * 8;
    }

    // prologue: issue tile-0 loads
#pragma unroll
    for (int s = 0; s < 4; ++s) ra[s] = *(const uint4*)(sa[s]);
#pragma unroll
    for (int s = 0; s < 4; ++s) rb[s] = *(const uint4*)(sb[s]);

    for (int kt = 0; kt < K; kt += BKK) {
        // write staged regs -> LDS (linear, conflict-free b128 writes)
#pragma unroll
        for (int s = 0; s < 4; ++s) *(uint4*)(lA + (s * 256 + t) * 8) = ra[s];
#pragma unroll
        for (int s = 0; s < 4; ++s) *(uint4*)(lB + (s * 256 + t) * 8) = rb[s];
        __syncthreads();  // LDS tile ready for all waves

        // issue NEXT tile's loads: they land during MFMA + barrier below
        if (kt + BKK < K) {
            const int kn = kt + BKK;
#pragma unroll
            for (int s = 0; s < 4; ++s) ra[s] = *(const uint4*)(sa[s] + kn);
#pragma unroll
            for (int s = 0; s < 4; ++s) rb[s] = *(const uint4*)(sb[s] + kn);
        }

#pragma unroll
        for (int kk = 0; kk < BKK; kk += 32) {
            bf16x8 af[4], bb[4];
#pragma unroll
            for (int i = 0; i < 4; ++i) {
                int row = wm + i * 16 + fr;
                int kg = ((kk >> 3) + quad) ^ (fr & 7);
                af[i] = *(const bf16x8*)(lA + row * BKK + kg * 8);
            }
#pragma unroll
            for (int j = 0; j < 4; ++j) {
                int row = wn + j * 16 + fr;
                int kg = ((kk >> 3) + quad) ^ (fr & 7);
                bb[j] = *(const bf16x8*)(lB + row * BKK + kg * 8);
            }
#pragma unroll
            for (int i = 0; i < 4; ++i)
#pragma unroll
                for (int j = 0; j < 4; ++j)
                    acc[i][j] = __builtin_amdgcn_mfma_f32_16x16x32_bf16(bb[j], af[i], acc[i][j], 0, 0, 0);
        }
        __syncthreads();  // all waves done reading before next ds_write
    }
}

// ---------------- kernel 4: GEMM1 + bias + exact GELU -> h1T (bf16) ----------------
__global__ __launch_bounds__(256, 3) void gemm1(const u16* __restrict__ xnT,
                                                const u16* __restrict__ w1b,
                                                const float* __restrict__ b1,
                                                u16* __restrict__ h1T) {
    __shared__ uint4 lAq[BM * BKK / 8], lBq[BN * BKK / 8];  // 32 KiB total
    u16* lA = (u16*)lAq; u16* lB = (u16*)lBq;
    const int bx = blockIdx.x;
    // XCD swizzle: mt%8 == bx%8, the 8 nt's of one mt adjacent in dispatch.
    const int nt = (bx >> 3) & 7;
    const int mt = (bx & 7) | ((bx >> 6) << 3);
    const int t = threadIdx.x, lane = t & 63, wv = t >> 6;
    const int wm = (wv & 1) * 64, wn = (wv >> 1) * 64;
    const int fr = lane & 15, quad = lane >> 4;
    floatx4 acc[4][4];
#pragma unroll
    for (int i = 0; i < 4; ++i)
#pragma unroll
        for (int j = 0; j < 4; ++j) acc[i][j] = (floatx4){0.f, 0.f, 0.f, 0.f};

    gemm_core(xnT + (size_t)(mt * BM) * 512, w1b + (size_t)(nt * BN) * 512, 512,
              acc, lA, lB, wm, wn, fr, quad);

    // swapped layout: m <- col (fr), n <- row (quad*4 + reg)
    const int mb = mt * BM + wm + fr;
    const int nb = nt * BN + wn + quad * 4;
#pragma unroll
    for (int j = 0; j < 4; ++j) {
        const int n0 = nb + j * 16;
        const float4 bv = *(const float4*)(b1 + n0);
#pragma unroll
        for (int i = 0; i < 4; ++i) {
            const int m = mb + i * 16;
            ushort4 o;
            o.x = f2bf(gelu_exact(acc[i][j][0] + bv.x));
            o.y = f2bf(gelu_exact(acc[i][j][1] + bv.y));
            o.z = f2bf(gelu_exact(acc[i][j][2] + bv.z));
            o.w = f2bf(gelu_exact(acc[i][j][3] + bv.w));
            *(ushort4*)(h1T + (size_t)m * 1024 + n0) = o;
        }
    }
}

// ---------------- kernel 5: GEMM2 + bias + residual -> out (fp32) ----------------
__global__ __launch_bounds__(256, 3) void gemm2(const u16* __restrict__ w2b,
                                                const u16* __restrict__ h1T,
                                                const float* __restrict__ b2,
                                                const float* __restrict__ x,
                                                float* __restrict__ out, int b0) {
    __shared__ uint4 lAq[BM * BKK / 8], lBq[BN * BKK / 8];
    u16* lA = (u16*)lAq; u16* lB = (u16*)lBq;
    const int bx = blockIdx.x;
    // XCD swizzle: nt%8 == bx%8, the 4 mt's of one nt adjacent in dispatch.
    const int mt = (bx >> 3) & 3;
    const int nt = (bx & 7) | ((bx >> 5) << 3);
    const int t = threadIdx.x, lane = t & 63, wv = t >> 6;
    const int wm = (wv & 1) * 64, wn = (wv >> 1) * 64;
    const int fr = lane & 15, quad = lane >> 4;
    floatx4 acc[4][4];
#pragma unroll
    for (int i = 0; i < 4; ++i)
#pragma unroll
        for (int j = 0; j < 4; ++j) acc[i][j] = (floatx4){0.f, 0.f, 0.f, 0.f};

    gemm_core(w2b + (size_t)(mt * BM) * 1024, h1T + (size_t)(nt * BN) * 1024, 1024,
              acc, lA, lB, wm, wn, fr, quad);

    const int n0g = b0 * 4096 + nt * BN;  // global flat (b,l); tiles never straddle b
    const int b = n0g >> 12;
    const int l_base = n0g & 4095;
    // swapped layout: m <- col (fr) = channel c, n <- row (quad*4 + reg) = l offset
    const int mb = mt * BM + wm + fr;
    const int nb = wn + quad * 4;
#pragma unroll
    for (int i = 0; i < 4; ++i) {
        const int m = mb + i * 16;
        const float bv = b2[m];
        const size_t rowoff = ((size_t)(b * 512 + m)) * 4096 + l_base + nb;
#pragma unroll
        for (int j = 0; j < 4; ++j) {
            const float4 xv = *(const float4*)(x + rowoff + j * 16);
            float4 ov;
            ov.x = acc[i][j][0] + bv + xv.x;
            ov.y = acc[i][j][1] + bv + xv.y;
            ov.z = acc[i][j][2] + bv + xv.z;
            ov.w = acc[i][j][3] + bv + xv.w;
            *(float4*)(out + rowoff + j * 16) = ov;
        }
    }
}

extern "C" void kernel_launch(void* const* d_in, const int* in_sizes, int n_in,
                              void* d_out, int out_size, void* d_ws, size_t ws_size,
                              hipStream_t stream) {
    const float* x     = (const float*)d_in[0];
    const float* gamma = (const float*)d_in[1];
    const float* beta  = (const float*)d_in[2];
    const float* w1    = (const float*)d_in[3];
    const float* b1    = (const float*)d_in[4];
    const float* w2    = (const float*)d_in[5];
    const float* b2    = (const float*)d_in[6];
    float* out = (float*)d_out;

    char* ws = (char*)d_ws;
    float* pstats = (float*)ws;                    // 8 KB used
    u16* wb = (u16*)(ws + 65536);                  // 2 MiB: w1b then w2b
    char* chunkbase = ws + 65536 + (2u << 20);
    const size_t fixed = 65536 + (2u << 20);

    // choose smallest chunk count NC so xnT+h1T fit in ws
    const size_t per = (size_t)192 * 1024 * 1024;  // NC=1: 64 MiB xnT + 128 MiB h1T
    int NC = 16;
    if      (ws_size >= fixed + per)      NC = 1;
    else if (ws_size >= fixed + per / 2)  NC = 2;
    else if (ws_size >= fixed + per / 4)  NC = 4;
    else if (ws_size >= fixed + per / 8)  NC = 8;
    const int CB = 16 / NC;                        // batches per chunk
    u16* xnT = (u16*)chunkbase;
    u16* h1T = (u16*)(chunkbase + (size_t)CB * 4096 * 512 * 2);

    gn_stats_w<<<2048, 256, 0, stream>>>(x, pstats, w1, w2, wb);
    for (int ch = 0; ch < NC; ++ch) {
        const int b0 = ch * CB;
        gn_norm_tr<<<CB * 128, 256, 0, stream>>>(x, gamma, beta, pstats, xnT, b0);
        gemm1<<<CB * 32 * 8, 256, 0, stream>>>(xnT, wb, b1, h1T);
        gemm2<<<CB * 32 * 4, 256, 0, stream>>>(wb + 524288, h1T, b2, x, out, b0);
    }
}